// Round 1
// baseline (627.178 us; speedup 1.0000x reference)
//
#include <hip/hip_runtime.h>

#define B_ 256
#define L_ 512
#define D_ 768
#define C_ 10331
#define K_ 2304   // 3*D

// ---------------------------------------------------------------------------
// Kernel 1: gather + three disjoint masked means -> feats (B, 3D)
// One block per batch. Thread t owns dims {t, t+256, t+512}.
// Masks are uniform per position l, so branch is wave-uniform.
// ---------------------------------------------------------------------------
__global__ __launch_bounds__(256) void feats_kernel(
    const float* __restrict__ seq,        // (B, L, D)
    const int*   __restrict__ head_index, // (B, L)
    const int*   __restrict__ start,      // (B,)
    const int*   __restrict__ end,        // (B,)
    float*       __restrict__ feats)      // (B, 3D)
{
    const int b = blockIdx.x;
    const int t = threadIdx.x;

    __shared__ int idx_sh[L_];
    __shared__ int nz_sh;
    if (t == 0) nz_sh = 0;
    __syncthreads();

    int local_nz = 0;
    #pragma unroll
    for (int l = t; l < L_; l += 256) {
        int v = head_index[b * L_ + l];
        idx_sh[l] = v;
        local_nz += (v != 0) ? 1 : 0;
    }
    atomicAdd(&nz_sh, local_nz);
    __syncthreads();

    const int right_len = nz_sh;
    const int s = start[b];
    const int e = end[b];

    float acc0[3] = {0.f, 0.f, 0.f};   // left  : pos <  s
    float acc1[3] = {0.f, 0.f, 0.f};   // ment  : s <= pos < e
    float acc2[3] = {0.f, 0.f, 0.f};   // right : e <= pos < right_len

    const float* seqb = seq + (size_t)b * L_ * D_;
    for (int l = 0; l < L_; ++l) {
        int m;
        if (l < s)              m = 0;
        else if (l < e)         m = 1;
        else if (l < right_len) m = 2;
        else                    continue;   // uniform skip
        const float* row = seqb + (size_t)idx_sh[l] * D_;
        float v0 = row[t];
        float v1 = row[t + 256];
        float v2 = row[t + 512];
        if (m == 0)      { acc0[0] += v0; acc0[1] += v1; acc0[2] += v2; }
        else if (m == 1) { acc1[0] += v0; acc1[1] += v1; acc1[2] += v2; }
        else             { acc2[0] += v0; acc2[1] += v1; acc2[2] += v2; }
    }

    const int nl = s;
    const int nm = e - s;
    const int nr = right_len - e;
    const float rl = (nl > 0) ? 1.0f / (float)nl : 0.0f;
    const float rm = (nm > 0) ? 1.0f / (float)nm : 0.0f;
    const float rr = (nr > 0) ? 1.0f / (float)nr : 0.0f;

    float* fb = feats + (size_t)b * K_;
    fb[          t      ] = acc0[0] * rl;
    fb[          t + 256] = acc0[1] * rl;
    fb[          t + 512] = acc0[2] * rl;
    fb[D_      + t      ] = acc1[0] * rm;
    fb[D_      + t + 256] = acc1[1] * rm;
    fb[D_      + t + 512] = acc1[2] * rm;
    fb[2 * D_  + t      ] = acc2[0] * rr;
    fb[2 * D_  + t + 256] = acc2[1] * rr;
    fb[2 * D_  + t + 512] = acc2[2] * rr;
}

// ---------------------------------------------------------------------------
// Kernel 2: out[b,c] = feats[b,:] . W[c,:] + bias[c]
// Classic LDS-tiled fp32 GEMM: BM=64 (batch), BN=64 (C), BK=32,
// 256 threads, 4x4 micro-tile per thread.
// ---------------------------------------------------------------------------
#define BM 64
#define BN 64
#define BK 32

__global__ __launch_bounds__(256) void gemm_kernel(
    const float* __restrict__ A,    // (B_, K_)  feats
    const float* __restrict__ W,    // (C_, K_)
    const float* __restrict__ bias, // (C_,)
    float*       __restrict__ out)  // (B_, C_)
{
    __shared__ float As[BM][BK + 1];
    __shared__ float Bs[BN][BK + 1];

    const int row0 = blockIdx.y * BM;   // batch tile
    const int col0 = blockIdx.x * BN;   // C tile
    const int t  = threadIdx.x;
    const int tx = t & 15;
    const int ty = t >> 4;

    float acc[4][4] = {};

    for (int k0 = 0; k0 < K_; k0 += BK) {
        // stage A tile: 64x32 floats, 8 per thread, coalesced over kk
        #pragma unroll
        for (int i = 0; i < 8; ++i) {
            int li = t + i * 256;
            int r  = li >> 5;
            int kk = li & 31;
            As[r][kk] = A[(size_t)(row0 + r) * K_ + k0 + kk];
        }
        // stage W tile: 64x32 floats, guard c < C_
        #pragma unroll
        for (int i = 0; i < 8; ++i) {
            int li = t + i * 256;
            int r  = li >> 5;
            int kk = li & 31;
            int c  = col0 + r;
            Bs[r][kk] = (c < C_) ? W[(size_t)c * K_ + k0 + kk] : 0.0f;
        }
        __syncthreads();

        #pragma unroll
        for (int kk = 0; kk < BK; ++kk) {
            float a[4], bb[4];
            #pragma unroll
            for (int i = 0; i < 4; ++i) a[i]  = As[ty * 4 + i][kk];
            #pragma unroll
            for (int j = 0; j < 4; ++j) bb[j] = Bs[tx * 4 + j][kk];
            #pragma unroll
            for (int i = 0; i < 4; ++i)
                #pragma unroll
                for (int j = 0; j < 4; ++j)
                    acc[i][j] += a[i] * bb[j];
        }
        __syncthreads();
    }

    #pragma unroll
    for (int i = 0; i < 4; ++i) {
        int r = row0 + ty * 4 + i;
        #pragma unroll
        for (int j = 0; j < 4; ++j) {
            int c = col0 + tx * 4 + j;
            if (c < C_) out[(size_t)r * C_ + c] = acc[i][j] + bias[c];
        }
    }
}

// ---------------------------------------------------------------------------
extern "C" void kernel_launch(void* const* d_in, const int* in_sizes, int n_in,
                              void* d_out, int out_size, void* d_ws, size_t ws_size,
                              hipStream_t stream) {
    const float* seq        = (const float*)d_in[0];
    const int*   head_index = (const int*)  d_in[1];
    const int*   start      = (const int*)  d_in[2];
    const int*   end        = (const int*)  d_in[3];
    const float* W          = (const float*)d_in[4];
    const float* bias       = (const float*)d_in[5];
    float*       out        = (float*)d_out;

    float* feats = (float*)d_ws;   // B_ * K_ floats = 2.36 MB

    feats_kernel<<<dim3(B_), dim3(256), 0, stream>>>(seq, head_index, start, end, feats);

    dim3 grid((C_ + BN - 1) / BN, B_ / BM);   // (162, 4)
    gemm_kernel<<<grid, dim3(256), 0, stream>>>(feats, W, bias, out);
}

// Round 2
// 201.178 us; speedup vs baseline: 3.1175x; 3.1175x over previous
//
#include <hip/hip_runtime.h>

#define B_ 256
#define L_ 512
#define D_ 768
#define C_ 10331
#define K_ 2304   // 3*D

using v8bf = __attribute__((ext_vector_type(8))) __bf16;
using v4f  = __attribute__((ext_vector_type(4))) float;

__device__ __forceinline__ unsigned short f2bf(float f) {
    unsigned int u = __float_as_uint(f);
    unsigned int r = (u + 0x7FFFu + ((u >> 16) & 1u)) >> 16;   // RNE
    return (unsigned short)r;
}

// ---------------------------------------------------------------------------
// Kernel 1: gather + three disjoint masked means -> feats (B, 3D) in BF16.
// 192 threads; thread t owns dims [4t, 4t+4) via float4 loads.
// Three uniform-bound region loops, unrolled x4 for memory-level parallelism.
// ---------------------------------------------------------------------------
__global__ __launch_bounds__(192) void feats_kernel(
    const float* __restrict__ seq,        // (B, L, D)
    const int*   __restrict__ head_index, // (B, L)
    const int*   __restrict__ start,      // (B,)
    const int*   __restrict__ end,        // (B,)
    unsigned short* __restrict__ feats)   // (B, 3D) bf16
{
    const int b = blockIdx.x;
    const int t = threadIdx.x;

    __shared__ int idx_sh[L_];
    __shared__ int nz_sh;
    if (t == 0) nz_sh = 0;
    __syncthreads();

    int local_nz = 0;
    for (int l = t; l < L_; l += 192) {
        int v = head_index[b * L_ + l];
        idx_sh[l] = v;
        local_nz += (v != 0) ? 1 : 0;
    }
    atomicAdd(&nz_sh, local_nz);
    __syncthreads();

    const int right_len = nz_sh;
    const int s = start[b];
    const int e = end[b];

    const float4* seqb4 = reinterpret_cast<const float4*>(seq + (size_t)b * L_ * D_);
    // region bounds: [0,s), [s,e), [e,right_len)
    int lo[3] = {0, s, e};
    int hi[3] = {s, e, right_len};

    for (int reg = 0; reg < 3; ++reg) {
        float4 a0 = make_float4(0.f, 0.f, 0.f, 0.f);
        float4 a1 = a0, a2 = a0, a3 = a0;
        int l = lo[reg];
        const int h = hi[reg];
        for (; l + 4 <= h; l += 4) {
            int r0 = idx_sh[l], r1 = idx_sh[l + 1], r2 = idx_sh[l + 2], r3 = idx_sh[l + 3];
            float4 v0 = seqb4[(size_t)r0 * 192 + t];
            float4 v1 = seqb4[(size_t)r1 * 192 + t];
            float4 v2 = seqb4[(size_t)r2 * 192 + t];
            float4 v3 = seqb4[(size_t)r3 * 192 + t];
            a0.x += v0.x; a0.y += v0.y; a0.z += v0.z; a0.w += v0.w;
            a1.x += v1.x; a1.y += v1.y; a1.z += v1.z; a1.w += v1.w;
            a2.x += v2.x; a2.y += v2.y; a2.z += v2.z; a2.w += v2.w;
            a3.x += v3.x; a3.y += v3.y; a3.z += v3.z; a3.w += v3.w;
        }
        for (; l < h; ++l) {
            float4 v0 = seqb4[(size_t)idx_sh[l] * 192 + t];
            a0.x += v0.x; a0.y += v0.y; a0.z += v0.z; a0.w += v0.w;
        }
        int n = h - lo[reg];
        float rs = (n > 0) ? 1.0f / (float)n : 0.0f;
        float4 sum;
        sum.x = (a0.x + a1.x + a2.x + a3.x) * rs;
        sum.y = (a0.y + a1.y + a2.y + a3.y) * rs;
        sum.z = (a0.z + a1.z + a2.z + a3.z) * rs;
        sum.w = (a0.w + a1.w + a2.w + a3.w) * rs;
        ushort4 u;
        u.x = f2bf(sum.x); u.y = f2bf(sum.y); u.z = f2bf(sum.z); u.w = f2bf(sum.w);
        *(ushort4*)(&feats[(size_t)b * K_ + reg * D_ + 4 * t]) = u;
    }
}

// ---------------------------------------------------------------------------
// Kernel 2: out = feats(bf16) @ W(f32->bf16 on the fly)^T + bias, via MFMA.
// 128x128 tile, BK=32, 4 waves, each wave owns a 64x64 sub-tile (4x4 frags
// of 16x16x32). LDS rows padded to 40 bf16 (80 B) -> only free 2-way
// conflicts on ds_read_b128.
// ---------------------------------------------------------------------------
#define GBM 128
#define GBN 128
#define GBK 32
#define LDP 40   // padded row length in bf16 elems

__global__ __launch_bounds__(256) void mfma_gemm(
    const unsigned short* __restrict__ A,  // (B_, K_) bf16 feats
    const float* __restrict__ W,           // (C_, K_) fp32
    const float* __restrict__ bias,        // (C_,)
    float*       __restrict__ out)         // (B_, C_)
{
    __shared__ unsigned short As[GBM * LDP];   // 10240 B
    __shared__ unsigned short Bs[GBN * LDP];   // 10240 B

    const int t    = threadIdx.x;
    const int lane = t & 63;
    const int wave = t >> 6;
    const int wr   = wave >> 1;     // 0..1
    const int wc   = wave & 1;      // 0..1
    const int row0 = blockIdx.y * GBM;
    const int col0 = blockIdx.x * GBN;

    const int frow = lane & 15;          // fragment row within 16
    const int fk   = (lane >> 4) * 8;    // fragment k offset (elems)

    v4f acc[4][4] = {};

    for (int k0 = 0; k0 < K_; k0 += GBK) {
        // ---- stage A: 128x32 bf16 = 512 groups of 8; 2 groups/thread ----
        #pragma unroll
        for (int i = 0; i < 2; ++i) {
            int g  = t + i * 256;
            int r  = g >> 2;
            int kg = (g & 3) * 8;
            int4 v = *(const int4*)(A + (size_t)(row0 + r) * K_ + k0 + kg);
            *(int4*)(&As[r * LDP + kg]) = v;
        }
        // ---- stage B: 128x32 fp32 -> bf16; 1024 float4 chunks; 4/thread ----
        #pragma unroll
        for (int i = 0; i < 4; ++i) {
            int c   = t + i * 256;
            int r   = c >> 3;
            int kq  = (c & 7) * 4;
            int col = col0 + r;
            float4 v = make_float4(0.f, 0.f, 0.f, 0.f);
            if (col < C_) v = *(const float4*)(W + (size_t)col * K_ + k0 + kq);
            ushort4 u;
            u.x = f2bf(v.x); u.y = f2bf(v.y); u.z = f2bf(v.z); u.w = f2bf(v.w);
            *(ushort4*)(&Bs[r * LDP + kq]) = u;
        }
        __syncthreads();

        v8bf af[4], bf[4];
        #pragma unroll
        for (int m = 0; m < 4; ++m) {
            int r = wr * 64 + m * 16 + frow;
            af[m] = *(const v8bf*)(&As[r * LDP + fk]);
        }
        #pragma unroll
        for (int n = 0; n < 4; ++n) {
            int r = wc * 64 + n * 16 + frow;
            bf[n] = *(const v8bf*)(&Bs[r * LDP + fk]);
        }
        #pragma unroll
        for (int m = 0; m < 4; ++m)
            #pragma unroll
            for (int n = 0; n < 4; ++n)
                acc[m][n] = __builtin_amdgcn_mfma_f32_16x16x32_bf16(af[m], bf[n], acc[m][n], 0, 0, 0);
        __syncthreads();
    }

    // ---- epilogue: D frag (m,n): row = (lane>>4)*4 + r, col = lane&15 ----
    const int crow = row0 + wr * 64 + (lane >> 4) * 4;
    const int ccol = col0 + wc * 64 + (lane & 15);
    #pragma unroll
    for (int n = 0; n < 4; ++n) {
        int col = ccol + n * 16;
        if (col < C_) {
            float bv = bias[col];
            #pragma unroll
            for (int m = 0; m < 4; ++m) {
                #pragma unroll
                for (int r = 0; r < 4; ++r) {
                    int row = crow + m * 16 + r;
                    out[(size_t)row * C_ + col] = acc[m][n][r] + bv;
                }
            }
        }
    }
}

// ---------------------------------------------------------------------------
extern "C" void kernel_launch(void* const* d_in, const int* in_sizes, int n_in,
                              void* d_out, int out_size, void* d_ws, size_t ws_size,
                              hipStream_t stream) {
    const float* seq        = (const float*)d_in[0];
    const int*   head_index = (const int*)  d_in[1];
    const int*   start      = (const int*)  d_in[2];
    const int*   end        = (const int*)  d_in[3];
    const float* W          = (const float*)d_in[4];
    const float* bias       = (const float*)d_in[5];
    float*       out        = (float*)d_out;

    unsigned short* feats = (unsigned short*)d_ws;   // B_*K_ bf16 = 1.18 MB

    feats_kernel<<<dim3(B_), dim3(192), 0, stream>>>(seq, head_index, start, end, feats);

    dim3 grid((C_ + GBN - 1) / GBN, B_ / GBM);   // (81, 2)
    mfma_gemm<<<grid, dim3(256), 0, stream>>>(feats, W, bias, out);
}

// Round 3
// 148.273 us; speedup vs baseline: 4.2299x; 1.3568x over previous
//
#include <hip/hip_runtime.h>

#define B_ 256
#define L_ 512
#define D_ 768
#define C_ 10331
#define K_ 2304           // 3*D
#define CPAD 10368        // 162*64, padded C for partials
#define NSLICE 4
#define KSL (K_ / NSLICE) // 576
#define GBK 64
#define NKIT (KSL / GBK)  // 9
#define LDPA 72           // padded LDS row (bf16 elems) for 64-wide K tile

using v8bf = __attribute__((ext_vector_type(8))) __bf16;
using v4f  = __attribute__((ext_vector_type(4))) float;

__device__ __forceinline__ unsigned short f2bf(float f) {
    unsigned int u = __float_as_uint(f);
    unsigned int r = (u + 0x7FFFu + ((u >> 16) & 1u)) >> 16;   // RNE
    return (unsigned short)r;
}

// ---------------------------------------------------------------------------
// Kernel 1a: per-(batch, row-chunk) partial region sums.
// grid (B_, 4); 192 threads; chunk handles gathered rows [64*chunk, 64*chunk+64).
// ---------------------------------------------------------------------------
__global__ __launch_bounds__(192) void feats_partial(
    const float* __restrict__ seq,        // (B, L, D)
    const int*   __restrict__ head_index, // (B, L)
    const int*   __restrict__ start,
    const int*   __restrict__ end,
    float*       __restrict__ pf)         // (B, 4, 3, D) f32 partials
{
    const int b = blockIdx.x, chunk = blockIdx.y, t = threadIdx.x;
    const int c0 = chunk * 64;

    __shared__ int idx_sh[64];
    __shared__ int nz_sh;
    if (t == 0) nz_sh = 0;
    __syncthreads();

    int local_nz = 0;
    for (int l = t; l < L_; l += 192) {
        int v = head_index[b * L_ + l];
        if (l >= c0 && l < c0 + 64) idx_sh[l - c0] = v;
        local_nz += (v != 0) ? 1 : 0;
    }
    atomicAdd(&nz_sh, local_nz);
    __syncthreads();

    const int right_len = nz_sh;
    const int s = start[b];
    const int e = end[b];
    int lo[3] = {0, s, e};
    int hi[3] = {s, e, right_len};

    const float4* seqb4 = reinterpret_cast<const float4*>(seq + (size_t)b * L_ * D_);

    for (int reg = 0; reg < 3; ++reg) {
        int l  = (lo[reg] > c0) ? lo[reg] : c0;
        int h  = (hi[reg] < c0 + 64) ? hi[reg] : c0 + 64;
        float4 a0 = make_float4(0.f,0.f,0.f,0.f);
        float4 a1 = a0, a2 = a0, a3 = a0;
        for (; l + 4 <= h; l += 4) {
            int r0 = idx_sh[l-c0], r1 = idx_sh[l-c0+1], r2 = idx_sh[l-c0+2], r3 = idx_sh[l-c0+3];
            float4 v0 = seqb4[(size_t)r0 * 192 + t];
            float4 v1 = seqb4[(size_t)r1 * 192 + t];
            float4 v2 = seqb4[(size_t)r2 * 192 + t];
            float4 v3 = seqb4[(size_t)r3 * 192 + t];
            a0.x += v0.x; a0.y += v0.y; a0.z += v0.z; a0.w += v0.w;
            a1.x += v1.x; a1.y += v1.y; a1.z += v1.z; a1.w += v1.w;
            a2.x += v2.x; a2.y += v2.y; a2.z += v2.z; a2.w += v2.w;
            a3.x += v3.x; a3.y += v3.y; a3.z += v3.z; a3.w += v3.w;
        }
        for (; l < h; ++l) {
            float4 v0 = seqb4[(size_t)idx_sh[l-c0] * 192 + t];
            a0.x += v0.x; a0.y += v0.y; a0.z += v0.z; a0.w += v0.w;
        }
        float4 sum;
        sum.x = a0.x + a1.x + a2.x + a3.x;
        sum.y = a0.y + a1.y + a2.y + a3.y;
        sum.z = a0.z + a1.z + a2.z + a3.z;
        sum.w = a0.w + a1.w + a2.w + a3.w;
        float* dst = pf + (((size_t)b * 4 + chunk) * 3 + reg) * D_;
        ((float4*)dst)[t] = sum;
    }
}

// ---------------------------------------------------------------------------
// Kernel 1b: combine 4 chunk partials -> mean -> bf16 feats (B, 3D)
// ---------------------------------------------------------------------------
__global__ __launch_bounds__(192) void feats_combine(
    const float* __restrict__ pf,
    const int*   __restrict__ head_index,
    const int*   __restrict__ start,
    const int*   __restrict__ end,
    unsigned short* __restrict__ feats)   // (B, 3D) bf16
{
    const int b = blockIdx.x, t = threadIdx.x;
    __shared__ int nz_sh;
    if (t == 0) nz_sh = 0;
    __syncthreads();
    int local_nz = 0;
    for (int l = t; l < L_; l += 192)
        local_nz += (head_index[b * L_ + l] != 0) ? 1 : 0;
    atomicAdd(&nz_sh, local_nz);
    __syncthreads();

    const int right_len = nz_sh;
    const int s = start[b], e = end[b];
    int cnt[3] = {s, e - s, right_len - e};

    for (int reg = 0; reg < 3; ++reg) {
        float4 acc = make_float4(0.f,0.f,0.f,0.f);
        #pragma unroll
        for (int ch = 0; ch < 4; ++ch) {
            float4 v = ((const float4*)(pf + (((size_t)b*4 + ch)*3 + reg) * D_))[t];
            acc.x += v.x; acc.y += v.y; acc.z += v.z; acc.w += v.w;
        }
        float rs = (cnt[reg] > 0) ? 1.0f / (float)cnt[reg] : 0.0f;
        ushort4 u;
        u.x = f2bf(acc.x * rs); u.y = f2bf(acc.y * rs);
        u.z = f2bf(acc.z * rs); u.w = f2bf(acc.w * rs);
        *(ushort4*)(&feats[(size_t)b * K_ + reg * D_ + 4 * t]) = u;
    }
}

// ---------------------------------------------------------------------------
// Kernel 2: partial[ks] = feats(bf16, all 256 rows) @ W[:, kslice]^T
// tile: 256 rows x 64 cols, BK=64, 512 threads (8 waves = 4 row x 2 col),
// register prefetch of next K-tile issued before MFMA phase.
// W is read exactly ONCE across the whole kernel (per element).
// ---------------------------------------------------------------------------
__global__ __launch_bounds__(512) void mfma_gemm(
    const unsigned short* __restrict__ A,  // (B_, K_) bf16 feats
    const float* __restrict__ W,           // (C_, K_) fp32
    float*       __restrict__ part)        // (NSLICE, B_, CPAD) f32
{
    __shared__ unsigned short As[256 * LDPA];  // 36864 B
    __shared__ unsigned short Bs[64  * LDPA];  //  9216 B

    const int t    = threadIdx.x;
    const int lane = t & 63;
    const int wave = t >> 6;
    const int wr   = wave >> 1;      // 0..3 : 64-row chunk
    const int wc   = wave & 1;       // 0..1 : 32-col chunk
    const int col0 = blockIdx.x * 64;
    const int kbase = blockIdx.y * KSL;

    const int frow = lane & 15;
    const int fk   = (lane >> 4) * 8;

    v4f acc[4][2] = {};

    int4   ra[4];
    float4 rb[2];

    // ---- prefetch tile 0 into registers ----
    #pragma unroll
    for (int i = 0; i < 4; ++i) {
        int g = t + i * 512;            // 2048 groups of 8 bf16
        int r = g >> 3, kg = (g & 7) * 8;
        ra[i] = *(const int4*)(A + (size_t)r * K_ + kbase + kg);
    }
    #pragma unroll
    for (int i = 0; i < 2; ++i) {
        int c = t + i * 512;            // 1024 float4 chunks
        int r = c >> 4, kq = (c & 15) * 4;
        int col = col0 + r;
        rb[i] = (col < C_) ? *(const float4*)(W + (size_t)col * K_ + kbase + kq)
                           : make_float4(0.f,0.f,0.f,0.f);
    }

    for (int it = 0; it < NKIT; ++it) {
        // ---- write current tile regs -> LDS (B converts to bf16) ----
        #pragma unroll
        for (int i = 0; i < 4; ++i) {
            int g = t + i * 512;
            int r = g >> 3, kg = (g & 7) * 8;
            *(int4*)(&As[r * LDPA + kg]) = ra[i];
        }
        #pragma unroll
        for (int i = 0; i < 2; ++i) {
            int c = t + i * 512;
            int r = c >> 4, kq = (c & 15) * 4;
            ushort4 u;
            u.x = f2bf(rb[i].x); u.y = f2bf(rb[i].y);
            u.z = f2bf(rb[i].z); u.w = f2bf(rb[i].w);
            *(ushort4*)(&Bs[r * LDPA + kq]) = u;
        }
        __syncthreads();

        // ---- issue next-tile loads (in flight across MFMA + barrier) ----
        if (it + 1 < NKIT) {
            int k0 = kbase + (it + 1) * GBK;
            #pragma unroll
            for (int i = 0; i < 4; ++i) {
                int g = t + i * 512;
                int r = g >> 3, kg = (g & 7) * 8;
                ra[i] = *(const int4*)(A + (size_t)r * K_ + k0 + kg);
            }
            #pragma unroll
            for (int i = 0; i < 2; ++i) {
                int c = t + i * 512;
                int r = c >> 4, kq = (c & 15) * 4;
                int col = col0 + r;
                rb[i] = (col < C_) ? *(const float4*)(W + (size_t)col * K_ + k0 + kq)
                                   : make_float4(0.f,0.f,0.f,0.f);
            }
        }

        // ---- fragments + MFMA ----
        v8bf af[4][2], bfr[2][2];
        #pragma unroll
        for (int m = 0; m < 4; ++m)
            #pragma unroll
            for (int kk = 0; kk < 2; ++kk)
                af[m][kk] = *(const v8bf*)(&As[(wr*64 + m*16 + frow) * LDPA + kk*32 + fk]);
        #pragma unroll
        for (int n = 0; n < 2; ++n)
            #pragma unroll
            for (int kk = 0; kk < 2; ++kk)
                bfr[n][kk] = *(const v8bf*)(&Bs[(wc*32 + n*16 + frow) * LDPA + kk*32 + fk]);
        #pragma unroll
        for (int kk = 0; kk < 2; ++kk)
            #pragma unroll
            for (int m = 0; m < 4; ++m)
                #pragma unroll
                for (int n = 0; n < 2; ++n)
                    acc[m][n] = __builtin_amdgcn_mfma_f32_16x16x32_bf16(af[m][kk], bfr[n][kk], acc[m][n], 0, 0, 0);
        __syncthreads();
    }

    // ---- epilogue: write fp32 partial (padded C, unguarded) ----
    float* p = part + (size_t)blockIdx.y * B_ * CPAD;
    const int crow = wr * 64 + (lane >> 4) * 4;
    const int ccol = col0 + wc * 32 + (lane & 15);
    #pragma unroll
    for (int n = 0; n < 2; ++n) {
        int col = ccol + n * 16;
        #pragma unroll
        for (int m = 0; m < 4; ++m)
            #pragma unroll
            for (int r = 0; r < 4; ++r)
                p[(size_t)(crow + m*16 + r) * CPAD + col] = acc[m][n][r];
    }
}

// ---------------------------------------------------------------------------
// Kernel 3: out[b,c] = sum_s part[s][b][c] + bias[c]
// ---------------------------------------------------------------------------
__global__ __launch_bounds__(256) void reduce_bias(
    const float* __restrict__ part,
    const float* __restrict__ bias,
    float*       __restrict__ out)
{
    const int row = blockIdx.x;
    const int t = threadIdx.x;
    const int NQ = CPAD / 4;   // 2592

    const float4* p0 = (const float4*)(part + (size_t)0 * B_ * CPAD + (size_t)row * CPAD);
    const float4* p1 = (const float4*)(part + (size_t)1 * B_ * CPAD + (size_t)row * CPAD);
    const float4* p2 = (const float4*)(part + (size_t)2 * B_ * CPAD + (size_t)row * CPAD);
    const float4* p3 = (const float4*)(part + (size_t)3 * B_ * CPAD + (size_t)row * CPAD);
    float* orow = out + (size_t)row * C_;

    for (int c4 = t; c4 < NQ; c4 += 256) {
        float4 a = p0[c4], b = p1[c4], c = p2[c4], d = p3[c4];
        float s0 = a.x + b.x + c.x + d.x;
        float s1 = a.y + b.y + c.y + d.y;
        float s2 = a.z + b.z + c.z + d.z;
        float s3 = a.w + b.w + c.w + d.w;
        int cc = c4 * 4;
        if (cc + 3 < C_) {
            float4 bv = ((const float4*)bias)[c4];
            orow[cc + 0] = s0 + bv.x;
            orow[cc + 1] = s1 + bv.y;
            orow[cc + 2] = s2 + bv.z;
            orow[cc + 3] = s3 + bv.w;
        } else {
            if (cc + 0 < C_) orow[cc + 0] = s0 + bias[cc + 0];
            if (cc + 1 < C_) orow[cc + 1] = s1 + bias[cc + 1];
            if (cc + 2 < C_) orow[cc + 2] = s2 + bias[cc + 2];
            if (cc + 3 < C_) orow[cc + 3] = s3 + bias[cc + 3];
        }
    }
}

// ---------------------------------------------------------------------------
extern "C" void kernel_launch(void* const* d_in, const int* in_sizes, int n_in,
                              void* d_out, int out_size, void* d_ws, size_t ws_size,
                              hipStream_t stream) {
    const float* seq        = (const float*)d_in[0];
    const int*   head_index = (const int*)  d_in[1];
    const int*   start      = (const int*)  d_in[2];
    const int*   end        = (const int*)  d_in[3];
    const float* W          = (const float*)d_in[4];
    const float* bias       = (const float*)d_in[5];
    float*       out        = (float*)d_out;

    unsigned short* feats = (unsigned short*)d_ws;                    // 1.18 MB
    float* pf   = (float*)((char*)d_ws + ((size_t)4  << 20));         // 9.44 MB
    float* part = (float*)((char*)d_ws + ((size_t)16 << 20));         // 42.5 MB

    feats_partial<<<dim3(B_, 4), dim3(192), 0, stream>>>(seq, head_index, start, end, pf);
    feats_combine<<<dim3(B_),    dim3(192), 0, stream>>>(pf, head_index, start, end, feats);

    dim3 grid((CPAD / 64), NSLICE);   // (162, 4) = 648 blocks
    mfma_gemm<<<grid, dim3(512), 0, stream>>>(feats, W, part);

    reduce_bias<<<dim3(B_), dim3(256), 0, stream>>>(part, bias, out);
}

// Round 4
// 135.707 us; speedup vs baseline: 4.6216x; 1.0926x over previous
//
#include <hip/hip_runtime.h>

#define B_ 256
#define L_ 512
#define D_ 768
#define C_ 10331
#define K_ 2304           // 3*D
#define CPAD 10368        // 162*64
#define NSLICE 3
#define KSL (K_ / NSLICE) // 768
#define GBK 64
#define NKIT (KSL / GBK)  // 12
#define LDPA 72           // padded LDS row (bf16 elems)
#define NCHUNK 8
#define CHROWS 32         // gathered rows per feats block

using v8bf = __attribute__((ext_vector_type(8))) __bf16;
using v4f  = __attribute__((ext_vector_type(4))) float;

__device__ __forceinline__ unsigned short f2bf(float f) {
    unsigned int u = __float_as_uint(f);
    unsigned int r = (u + 0x7FFFu + ((u >> 16) & 1u)) >> 16;   // RNE
    return (unsigned short)r;
}

// ---------------------------------------------------------------------------
// Kernel 1a: per-(batch, 32-row chunk) partial region sums -> pf (B,8,3,D) f32
// grid (B_, 8), 192 threads. High block count for latency hiding.
// ---------------------------------------------------------------------------
__global__ __launch_bounds__(192) void feats_partial(
    const float* __restrict__ seq,        // (B, L, D)
    const int*   __restrict__ head_index, // (B, L)
    const int*   __restrict__ start,
    const int*   __restrict__ end,
    float*       __restrict__ pf)         // (B, 8, 3, D)
{
    const int b = blockIdx.x, chunk = blockIdx.y, t = threadIdx.x;
    const int c0 = chunk * CHROWS;

    __shared__ int idx_sh[CHROWS];
    __shared__ int nz_sh;
    if (t == 0) nz_sh = 0;
    __syncthreads();

    int local_nz = 0;
    for (int l = t; l < L_; l += 192) {
        int v = head_index[b * L_ + l];
        if (l >= c0 && l < c0 + CHROWS) idx_sh[l - c0] = v;
        local_nz += (v != 0) ? 1 : 0;
    }
    atomicAdd(&nz_sh, local_nz);
    __syncthreads();

    const int right_len = nz_sh;
    const int s = start[b];
    const int e = end[b];
    int lo[3] = {0, s, e};
    int hi[3] = {s, e, right_len};

    const float4* seqb4 = reinterpret_cast<const float4*>(seq + (size_t)b * L_ * D_);

    for (int reg = 0; reg < 3; ++reg) {
        int l = (lo[reg] > c0) ? lo[reg] : c0;
        int h = (hi[reg] < c0 + CHROWS) ? hi[reg] : c0 + CHROWS;
        float4 a0 = make_float4(0.f,0.f,0.f,0.f);
        float4 a1 = a0, a2 = a0, a3 = a0;
        for (; l + 4 <= h; l += 4) {
            int r0 = idx_sh[l-c0], r1 = idx_sh[l-c0+1], r2 = idx_sh[l-c0+2], r3 = idx_sh[l-c0+3];
            float4 v0 = seqb4[(size_t)r0 * 192 + t];
            float4 v1 = seqb4[(size_t)r1 * 192 + t];
            float4 v2 = seqb4[(size_t)r2 * 192 + t];
            float4 v3 = seqb4[(size_t)r3 * 192 + t];
            a0.x += v0.x; a0.y += v0.y; a0.z += v0.z; a0.w += v0.w;
            a1.x += v1.x; a1.y += v1.y; a1.z += v1.z; a1.w += v1.w;
            a2.x += v2.x; a2.y += v2.y; a2.z += v2.z; a2.w += v2.w;
            a3.x += v3.x; a3.y += v3.y; a3.z += v3.z; a3.w += v3.w;
        }
        for (; l < h; ++l) {
            float4 v0 = seqb4[(size_t)idx_sh[l-c0] * 192 + t];
            a0.x += v0.x; a0.y += v0.y; a0.z += v0.z; a0.w += v0.w;
        }
        float4 sum;
        sum.x = a0.x + a1.x + a2.x + a3.x;
        sum.y = a0.y + a1.y + a2.y + a3.y;
        sum.z = a0.z + a1.z + a2.z + a3.z;
        sum.w = a0.w + a1.w + a2.w + a3.w;
        float* dst = pf + (((size_t)b * NCHUNK + chunk) * 3 + reg) * D_;
        ((float4*)dst)[t] = sum;
    }
}

// ---------------------------------------------------------------------------
// Kernel 1b: combine 8 chunk partials -> mean -> bf16 feats (B, 3D)
// ---------------------------------------------------------------------------
__global__ __launch_bounds__(192) void feats_combine(
    const float* __restrict__ pf,
    const int*   __restrict__ head_index,
    const int*   __restrict__ start,
    const int*   __restrict__ end,
    unsigned short* __restrict__ feats)   // (B, 3D) bf16
{
    const int b = blockIdx.x, t = threadIdx.x;
    __shared__ int nz_sh;
    if (t == 0) nz_sh = 0;
    __syncthreads();
    int local_nz = 0;
    for (int l = t; l < L_; l += 192)
        local_nz += (head_index[b * L_ + l] != 0) ? 1 : 0;
    atomicAdd(&nz_sh, local_nz);
    __syncthreads();

    const int right_len = nz_sh;
    const int s = start[b], e = end[b];
    int cnt[3] = {s, e - s, right_len - e};

    for (int reg = 0; reg < 3; ++reg) {
        float4 acc = make_float4(0.f,0.f,0.f,0.f);
        #pragma unroll
        for (int ch = 0; ch < NCHUNK; ++ch) {
            float4 v = ((const float4*)(pf + (((size_t)b*NCHUNK + ch)*3 + reg) * D_))[t];
            acc.x += v.x; acc.y += v.y; acc.z += v.z; acc.w += v.w;
        }
        float rs = (cnt[reg] > 0) ? 1.0f / (float)cnt[reg] : 0.0f;
        ushort4 u;
        u.x = f2bf(acc.x * rs); u.y = f2bf(acc.y * rs);
        u.z = f2bf(acc.z * rs); u.w = f2bf(acc.w * rs);
        *(ushort4*)(&feats[(size_t)b * K_ + reg * D_ + 4 * t]) = u;
    }
}

// ---------------------------------------------------------------------------
// Kernel 2: partial[ks] = feats(bf16, all 256 rows) @ W[:, kslice]^T
// tile 256x64, BK=64, 512 threads (8 waves = 4 row x 2 col), register
// prefetch of next K-tile. NSLICE=3 -> 486 blocks ~= 2 balanced passes/CU.
// ---------------------------------------------------------------------------
__global__ __launch_bounds__(512, 4) void mfma_gemm(
    const unsigned short* __restrict__ A,  // (B_, K_) bf16
    const float* __restrict__ W,           // (C_, K_) fp32
    float*       __restrict__ part)        // (NSLICE, B_, CPAD) f32
{
    __shared__ unsigned short As[256 * LDPA];  // 36864 B
    __shared__ unsigned short Bs[64  * LDPA];  //  9216 B

    const int t    = threadIdx.x;
    const int lane = t & 63;
    const int wave = t >> 6;
    const int wr   = wave >> 1;      // 0..3
    const int wc   = wave & 1;       // 0..1
    const int col0 = blockIdx.x * 64;
    const int kbase = blockIdx.y * KSL;

    const int frow = lane & 15;
    const int fk   = (lane >> 4) * 8;

    v4f acc[4][2] = {};
    int4   ra[4];
    float4 rb[2];

    #pragma unroll
    for (int i = 0; i < 4; ++i) {
        int g = t + i * 512;
        int r = g >> 3, kg = (g & 7) * 8;
        ra[i] = *(const int4*)(A + (size_t)r * K_ + kbase + kg);
    }
    #pragma unroll
    for (int i = 0; i < 2; ++i) {
        int c = t + i * 512;
        int r = c >> 4, kq = (c & 15) * 4;
        int col = col0 + r;
        rb[i] = (col < C_) ? *(const float4*)(W + (size_t)col * K_ + kbase + kq)
                           : make_float4(0.f,0.f,0.f,0.f);
    }

    for (int it = 0; it < NKIT; ++it) {
        #pragma unroll
        for (int i = 0; i < 4; ++i) {
            int g = t + i * 512;
            int r = g >> 3, kg = (g & 7) * 8;
            *(int4*)(&As[r * LDPA + kg]) = ra[i];
        }
        #pragma unroll
        for (int i = 0; i < 2; ++i) {
            int c = t + i * 512;
            int r = c >> 4, kq = (c & 15) * 4;
            ushort4 u;
            u.x = f2bf(rb[i].x); u.y = f2bf(rb[i].y);
            u.z = f2bf(rb[i].z); u.w = f2bf(rb[i].w);
            *(ushort4*)(&Bs[r * LDPA + kq]) = u;
        }
        __syncthreads();

        if (it + 1 < NKIT) {
            int k0 = kbase + (it + 1) * GBK;
            #pragma unroll
            for (int i = 0; i < 4; ++i) {
                int g = t + i * 512;
                int r = g >> 3, kg = (g & 7) * 8;
                ra[i] = *(const int4*)(A + (size_t)r * K_ + k0 + kg);
            }
            #pragma unroll
            for (int i = 0; i < 2; ++i) {
                int c = t + i * 512;
                int r = c >> 4, kq = (c & 15) * 4;
                int col = col0 + r;
                rb[i] = (col < C_) ? *(const float4*)(W + (size_t)col * K_ + k0 + kq)
                                   : make_float4(0.f,0.f,0.f,0.f);
            }
        }

        v8bf af[4][2], bfr[2][2];
        #pragma unroll
        for (int m = 0; m < 4; ++m)
            #pragma unroll
            for (int kk = 0; kk < 2; ++kk)
                af[m][kk] = *(const v8bf*)(&As[(wr*64 + m*16 + frow) * LDPA + kk*32 + fk]);
        #pragma unroll
        for (int n = 0; n < 2; ++n)
            #pragma unroll
            for (int kk = 0; kk < 2; ++kk)
                bfr[n][kk] = *(const v8bf*)(&Bs[(wc*32 + n*16 + frow) * LDPA + kk*32 + fk]);
        #pragma unroll
        for (int kk = 0; kk < 2; ++kk)
            #pragma unroll
            for (int m = 0; m < 4; ++m)
                #pragma unroll
                for (int n = 0; n < 2; ++n)
                    acc[m][n] = __builtin_amdgcn_mfma_f32_16x16x32_bf16(af[m][kk], bfr[n][kk], acc[m][n], 0, 0, 0);
        __syncthreads();
    }

    float* p = part + (size_t)blockIdx.y * B_ * CPAD;
    const int crow = wr * 64 + (lane >> 4) * 4;
    const int ccol = col0 + wc * 32 + (lane & 15);
    #pragma unroll
    for (int n = 0; n < 2; ++n) {
        int col = ccol + n * 16;
        #pragma unroll
        for (int m = 0; m < 4; ++m)
            #pragma unroll
            for (int r = 0; r < 4; ++r)
                p[(size_t)(crow + m*16 + r) * CPAD + col] = acc[m][n][r];
    }
}

// ---------------------------------------------------------------------------
// Kernel 3: out[b,c] = sum_s part[s][b][c] + bias[c]; 512 blocks (half-rows)
// ---------------------------------------------------------------------------
__global__ __launch_bounds__(256) void reduce_bias(
    const float* __restrict__ part,
    const float* __restrict__ bias,
    float*       __restrict__ out)
{
    const int row  = blockIdx.x >> 1;
    const int half = blockIdx.x & 1;
    const int t = threadIdx.x;
    const int NQ  = CPAD / 4;        // 2592
    const int NQ2 = NQ / 2;          // 1296

    const float4* p0 = (const float4*)(part + (size_t)0 * B_ * CPAD + (size_t)row * CPAD);
    const float4* p1 = (const float4*)(part + (size_t)1 * B_ * CPAD + (size_t)row * CPAD);
    const float4* p2 = (const float4*)(part + (size_t)2 * B_ * CPAD + (size_t)row * CPAD);
    float* orow = out + (size_t)row * C_;

    const int c4lo = half * NQ2, c4hi = c4lo + NQ2;
    for (int c4 = c4lo + t; c4 < c4hi; c4 += 256) {
        float4 a = p0[c4], b = p1[c4], c = p2[c4];
        float s0 = a.x + b.x + c.x;
        float s1 = a.y + b.y + c.y;
        float s2 = a.z + b.z + c.z;
        float s3 = a.w + b.w + c.w;
        int cc = c4 * 4;
        if (cc + 3 < C_) {
            float4 bv = ((const float4*)bias)[c4];
            orow[cc + 0] = s0 + bv.x;
            orow[cc + 1] = s1 + bv.y;
            orow[cc + 2] = s2 + bv.z;
            orow[cc + 3] = s3 + bv.w;
        } else {
            if (cc + 0 < C_) orow[cc + 0] = s0 + bias[cc + 0];
            if (cc + 1 < C_) orow[cc + 1] = s1 + bias[cc + 1];
            if (cc + 2 < C_) orow[cc + 2] = s2 + bias[cc + 2];
            if (cc + 3 < C_) orow[cc + 3] = s3 + bias[cc + 3];
        }
    }
}

// ---------------------------------------------------------------------------
extern "C" void kernel_launch(void* const* d_in, const int* in_sizes, int n_in,
                              void* d_out, int out_size, void* d_ws, size_t ws_size,
                              hipStream_t stream) {
    const float* seq        = (const float*)d_in[0];
    const int*   head_index = (const int*)  d_in[1];
    const int*   start      = (const int*)  d_in[2];
    const int*   end        = (const int*)  d_in[3];
    const float* W          = (const float*)d_in[4];
    const float* bias       = (const float*)d_in[5];
    float*       out        = (float*)d_out;

    unsigned short* feats = (unsigned short*)d_ws;                    // 1.18 MB
    float* pf   = (float*)((char*)d_ws + ((size_t)2  << 20));         // 18.9 MB
    float* part = (float*)((char*)d_ws + ((size_t)24 << 20));         // 31.9 MB

    feats_partial<<<dim3(B_, NCHUNK), dim3(192), 0, stream>>>(seq, head_index, start, end, pf);
    feats_combine<<<dim3(B_),         dim3(192), 0, stream>>>(pf, head_index, start, end, feats);

    dim3 grid(CPAD / 64, NSLICE);   // (162, 3) = 486 blocks
    mfma_gemm<<<grid, dim3(512), 0, stream>>>(feats, W, part);

    reduce_bias<<<dim3(B_ * 2), dim3(256), 0, stream>>>(part, bias, out);
}

// Round 5
// 134.728 us; speedup vs baseline: 4.6552x; 1.0073x over previous
//
#include <hip/hip_runtime.h>

#define B_ 256
#define L_ 512
#define D_ 768
#define C_ 10331
#define K_ 2304           // 3*D
#define GBK 64
#define NKIT (K_ / GBK)   // 36
#define LDPA 72           // padded LDS row (bf16 elems)

using v8bf = __attribute__((ext_vector_type(8))) __bf16;
using v4f  = __attribute__((ext_vector_type(4))) float;

__device__ __forceinline__ unsigned short f2bf(float f) {
    unsigned int u = __float_as_uint(f);
    unsigned int r = (u + 0x7FFFu + ((u >> 16) & 1u)) >> 16;   // RNE
    return (unsigned short)r;
}

__device__ __forceinline__ void fma4(float4& a, float w, const float4& v) {
    a.x = fmaf(w, v.x, a.x); a.y = fmaf(w, v.y, a.y);
    a.z = fmaf(w, v.z, a.z); a.w = fmaf(w, v.w, a.w);
}

// ---------------------------------------------------------------------------
// Kernel 1: count-based gather + masked means -> feats (B, 3D) bf16.
// grid (B, 3): block (b, dc) computes dims [256*dc, 256*dc+256) of all 3
// region means. Histogram head_index -> per-region counts over 512 rows,
// compact rows with any count (ascending!), stream them once, weight-FMA.
// 256 threads = 4 waves; wave = row-group; lane = float4 within slice.
// ---------------------------------------------------------------------------
__global__ __launch_bounds__(256) void feats_gather(
    const float* __restrict__ seq,        // (B, L, D)
    const int*   __restrict__ head_index, // (B, L)
    const int*   __restrict__ start,
    const int*   __restrict__ end,
    unsigned short* __restrict__ feats)   // (B, 3D) bf16
{
    const int b    = blockIdx.x;
    const int dc   = blockIdx.y;          // 0..2, 256-dim slice
    const int t    = threadIdx.x;
    const int lane = t & 63;
    const int wave = t >> 6;

    __shared__ int idx_sh[L_];
    __shared__ int cnt_sh[3][L_];
    __shared__ int list_sh[L_];
    __shared__ int nz_sh, nlist_sh;
    __shared__ float4 red_sh[4][3][64];

    // ---- stage head_index, zero counts, count nonzeros ----
    if (t == 0) nz_sh = 0;
    #pragma unroll
    for (int i = 0; i < 6; ++i) cnt_sh[0][t + i * 256 >= L_ ? 0 : 0] = 0; // dummy
    // (proper zeroing below)
    for (int j = t; j < L_; j += 256) {
        cnt_sh[0][j] = 0; cnt_sh[1][j] = 0; cnt_sh[2][j] = 0;
    }
    int local_nz = 0;
    for (int l = t; l < L_; l += 256) {
        int v = head_index[b * L_ + l];
        idx_sh[l] = v;
        local_nz += (v != 0) ? 1 : 0;
    }
    atomicAdd(&nz_sh, local_nz);
    __syncthreads();

    const int right_len = nz_sh;
    const int s = start[b];
    const int e = end[b];

    // ---- histogram positions [0, right_len) into 3 region count arrays ----
    for (int l = t; l < right_len; l += 256) {
        int r = (l < s) ? 0 : ((l < e) ? 1 : 2);
        atomicAdd(&cnt_sh[r][idx_sh[l]], 1);
    }
    __syncthreads();

    // ---- compact rows with any count, order-preserving (wave 0 only) ----
    if (wave == 0) {
        int maskbits = 0, csum = 0;
        const int j0 = lane * 8;
        #pragma unroll
        for (int k = 0; k < 8; ++k) {
            int j = j0 + k;
            int any = cnt_sh[0][j] | cnt_sh[1][j] | cnt_sh[2][j];
            if (any) { maskbits |= (1 << k); ++csum; }
        }
        int incl = csum;
        #pragma unroll
        for (int off = 1; off < 64; off <<= 1) {
            int v = __shfl_up(incl, off, 64);
            if (lane >= off) incl += v;
        }
        int pos = incl - csum;
        #pragma unroll
        for (int k = 0; k < 8; ++k)
            if (maskbits & (1 << k)) list_sh[pos++] = j0 + k;
        if (lane == 63) nlist_sh = incl;
    }
    __syncthreads();

    const int nlist = nlist_sh;
    const int nl = s, nm = e - s, nr = right_len - e;
    const float rs0 = (nl > 0) ? 1.0f / (float)nl : 0.0f;
    const float rs1 = (nm > 0) ? 1.0f / (float)nm : 0.0f;
    const float rs2 = (nr > 0) ? 1.0f / (float)nr : 0.0f;

    const float4* seqb4 = reinterpret_cast<const float4*>(seq + (size_t)b * L_ * D_);
    const int base4 = dc * 64 + lane;   // float4 index within a row

    float4 acc0 = make_float4(0.f,0.f,0.f,0.f);
    float4 acc1 = acc0, acc2 = acc0;

    // ---- stream compacted rows (ascending j), unroll x2 per wave ----
    int i = wave;
    for (; i + 4 < nlist; i += 8) {
        int j0 = list_sh[i], j1 = list_sh[i + 4];
        float4 v0 = seqb4[(size_t)j0 * 192 + base4];
        float4 v1 = seqb4[(size_t)j1 * 192 + base4];
        float w00 = (float)cnt_sh[0][j0] * rs0;
        float w01 = (float)cnt_sh[1][j0] * rs1;
        float w02 = (float)cnt_sh[2][j0] * rs2;
        float w10 = (float)cnt_sh[0][j1] * rs0;
        float w11 = (float)cnt_sh[1][j1] * rs1;
        float w12 = (float)cnt_sh[2][j1] * rs2;
        fma4(acc0, w00, v0); fma4(acc1, w01, v0); fma4(acc2, w02, v0);
        fma4(acc0, w10, v1); fma4(acc1, w11, v1); fma4(acc2, w12, v1);
    }
    if (i < nlist) {
        int j0 = list_sh[i];
        float4 v0 = seqb4[(size_t)j0 * 192 + base4];
        float w00 = (float)cnt_sh[0][j0] * rs0;
        float w01 = (float)cnt_sh[1][j0] * rs1;
        float w02 = (float)cnt_sh[2][j0] * rs2;
        fma4(acc0, w00, v0); fma4(acc1, w01, v0); fma4(acc2, w02, v0);
    }

    // ---- cross-wave reduce + bf16 store ----
    red_sh[wave][0][lane] = acc0;
    red_sh[wave][1][lane] = acc1;
    red_sh[wave][2][lane] = acc2;
    __syncthreads();

    if (t < 192) {
        int reg = t >> 6, ln = t & 63;
        float4 a = red_sh[0][reg][ln], bq = red_sh[1][reg][ln];
        float4 c = red_sh[2][reg][ln], d = red_sh[3][reg][ln];
        float4 sum;
        sum.x = a.x + bq.x + c.x + d.x;
        sum.y = a.y + bq.y + c.y + d.y;
        sum.z = a.z + bq.z + c.z + d.z;
        sum.w = a.w + bq.w + c.w + d.w;
        ushort4 u;
        u.x = f2bf(sum.x); u.y = f2bf(sum.y); u.z = f2bf(sum.z); u.w = f2bf(sum.w);
        *(ushort4*)(&feats[(size_t)b * K_ + reg * D_ + dc * 256 + 4 * ln]) = u;
    }
}

// ---------------------------------------------------------------------------
// Kernel 2: out = feats(bf16, 256 rows) @ W^T + bias, full K, direct write.
// tile 256x64, BK=64, 512 threads (8 waves = 4 row x 2 col), register
// prefetch of next K-tile. 162 blocks, one balanced pass; W read once.
// ---------------------------------------------------------------------------
__global__ __launch_bounds__(512) void mfma_gemm(
    const unsigned short* __restrict__ A,  // (B_, K_) bf16
    const float* __restrict__ W,           // (C_, K_) fp32
    const float* __restrict__ bias,        // (C_,)
    float*       __restrict__ out)         // (B_, C_) f32
{
    __shared__ unsigned short As[256 * LDPA];  // 36864 B
    __shared__ unsigned short Bs[64  * LDPA];  //  9216 B

    const int t    = threadIdx.x;
    const int lane = t & 63;
    const int wave = t >> 6;
    const int wr   = wave >> 1;      // 0..3
    const int wc   = wave & 1;       // 0..1
    const int col0 = blockIdx.x * 64;

    const int frow = lane & 15;
    const int fk   = (lane >> 4) * 8;

    v4f acc[4][2] = {};
    int4   ra[4];
    float4 rb[2];

    #pragma unroll
    for (int i = 0; i < 4; ++i) {
        int g = t + i * 512;
        int r = g >> 3, kg = (g & 7) * 8;
        ra[i] = *(const int4*)(A + (size_t)r * K_ + kg);
    }
    #pragma unroll
    for (int i = 0; i < 2; ++i) {
        int c = t + i * 512;
        int r = c >> 4, kq = (c & 15) * 4;
        int col = col0 + r;
        rb[i] = (col < C_) ? *(const float4*)(W + (size_t)col * K_ + kq)
                           : make_float4(0.f,0.f,0.f,0.f);
    }

    for (int it = 0; it < NKIT; ++it) {
        #pragma unroll
        for (int i = 0; i < 4; ++i) {
            int g = t + i * 512;
            int r = g >> 3, kg = (g & 7) * 8;
            *(int4*)(&As[r * LDPA + kg]) = ra[i];
        }
        #pragma unroll
        for (int i = 0; i < 2; ++i) {
            int c = t + i * 512;
            int r = c >> 4, kq = (c & 15) * 4;
            ushort4 u;
            u.x = f2bf(rb[i].x); u.y = f2bf(rb[i].y);
            u.z = f2bf(rb[i].z); u.w = f2bf(rb[i].w);
            *(ushort4*)(&Bs[r * LDPA + kq]) = u;
        }
        __syncthreads();

        if (it + 1 < NKIT) {
            int k0 = (it + 1) * GBK;
            #pragma unroll
            for (int i = 0; i < 4; ++i) {
                int g = t + i * 512;
                int r = g >> 3, kg = (g & 7) * 8;
                ra[i] = *(const int4*)(A + (size_t)r * K_ + k0 + kg);
            }
            #pragma unroll
            for (int i = 0; i < 2; ++i) {
                int c = t + i * 512;
                int r = c >> 4, kq = (c & 15) * 4;
                int col = col0 + r;
                rb[i] = (col < C_) ? *(const float4*)(W + (size_t)col * K_ + k0 + kq)
                                   : make_float4(0.f,0.f,0.f,0.f);
            }
        }

        v8bf af[4][2], bfr[2][2];
        #pragma unroll
        for (int m = 0; m < 4; ++m)
            #pragma unroll
            for (int kk = 0; kk < 2; ++kk)
                af[m][kk] = *(const v8bf*)(&As[(wr*64 + m*16 + frow) * LDPA + kk*32 + fk]);
        #pragma unroll
        for (int n = 0; n < 2; ++n)
            #pragma unroll
            for (int kk = 0; kk < 2; ++kk)
                bfr[n][kk] = *(const v8bf*)(&Bs[(wc*32 + n*16 + frow) * LDPA + kk*32 + fk]);
        #pragma unroll
        for (int kk = 0; kk < 2; ++kk)
            #pragma unroll
            for (int m = 0; m < 4; ++m)
                #pragma unroll
                for (int n = 0; n < 2; ++n)
                    acc[m][n] = __builtin_amdgcn_mfma_f32_16x16x32_bf16(af[m][kk], bfr[n][kk], acc[m][n], 0, 0, 0);
        __syncthreads();
    }

    // ---- epilogue: direct fp32 out + bias, col-guarded ----
    const int crow = wr * 64 + (lane >> 4) * 4;
    const int ccol = col0 + wc * 32 + (lane & 15);
    #pragma unroll
    for (int n = 0; n < 2; ++n) {
        int col = ccol + n * 16;
        if (col < C_) {
            float bv = bias[col];
            #pragma unroll
            for (int m = 0; m < 4; ++m)
                #pragma unroll
                for (int r = 0; r < 4; ++r)
                    out[(size_t)(crow + m*16 + r) * C_ + col] = acc[m][n][r] + bv;
        }
    }
}

// ---------------------------------------------------------------------------
extern "C" void kernel_launch(void* const* d_in, const int* in_sizes, int n_in,
                              void* d_out, int out_size, void* d_ws, size_t ws_size,
                              hipStream_t stream) {
    const float* seq        = (const float*)d_in[0];
    const int*   head_index = (const int*)  d_in[1];
    const int*   start      = (const int*)  d_in[2];
    const int*   end        = (const int*)  d_in[3];
    const float* W          = (const float*)d_in[4];
    const float* bias       = (const float*)d_in[5];
    float*       out        = (float*)d_out;

    unsigned short* feats = (unsigned short*)d_ws;   // B_*K_ bf16 = 1.18 MB

    feats_gather<<<dim3(B_, 3), dim3(256), 0, stream>>>(seq, head_index, start, end, feats);
    mfma_gemm<<<dim3(162), dim3(512), 0, stream>>>(feats, W, bias, out);
}